// Round 1
// 1400.734 us; speedup vs baseline: 1.0704x; 1.0704x over previous
//
#include <hip/hip_runtime.h>
#include <hip/hip_bf16.h>

typedef __bf16 v8bf __attribute__((ext_vector_type(8)));
typedef __bf16 v4bf __attribute__((ext_vector_type(4)));
typedef short v4ss __attribute__((ext_vector_type(4)));
typedef float v4f __attribute__((ext_vector_type(4)));

constexpr int B_ = 8, S_ = 1024, D_ = 1024, NH_ = 16, DH_ = 64;
constexpr float NEGV = -1e9f;

#define MFMA(a, b, c) __builtin_amdgcn_mfma_f32_16x16x32_bf16((a), (b), (c), 0, 0, 0)

// k=16 bf16 MFMA: builtin name varies across ROCm; instruction exists on gfx950.
__device__ __forceinline__ v4f mfma_k16(v4bf a, v4bf b, v4f c) {
#if __has_builtin(__builtin_amdgcn_mfma_f32_16x16x16bf16_1k)
  return __builtin_amdgcn_mfma_f32_16x16x16bf16_1k(
      __builtin_bit_cast(v4ss, a), __builtin_bit_cast(v4ss, b), c, 0, 0, 0);
#elif __has_builtin(__builtin_amdgcn_mfma_f32_16x16x16_bf16)
  return __builtin_amdgcn_mfma_f32_16x16x16_bf16(a, b, c, 0, 0, 0);
#else
  v4f d;
  asm volatile("v_mfma_f32_16x16x16_bf16 %0, %1, %2, %3\n\ts_nop 7\n\ts_nop 7"
               : "=v"(d)
               : "v"(a), "v"(b), "v"(c));
  return d;
#endif
}

__device__ __forceinline__ __bf16 tobf(float f) {
  unsigned u = __float_as_uint(f);
  u += 0x7fffu + ((u >> 16) & 1);
  unsigned short s = (unsigned short)(u >> 16);
  return __builtin_bit_cast(__bf16, s);
}

__device__ __forceinline__ v8bf cvt8(float4 a, float4 b) {
  v8bf r;
  r[0] = tobf(a.x); r[1] = tobf(a.y); r[2] = tobf(a.z); r[3] = tobf(a.w);
  r[4] = tobf(b.x); r[5] = tobf(b.y); r[6] = tobf(b.z); r[7] = tobf(b.w);
  return r;
}

// ---------------------------------------------------------------------------
// Kernel 0: pack mask (B,S,S) int32 -> bitmask u64 (bit t of row). 33.5MB -> 1MB
// ---------------------------------------------------------------------------
__global__ __launch_bounds__(256) void maskpack(const int* __restrict__ mask,
                                                unsigned long long* __restrict__ bits) {
  size_t base = (size_t)blockIdx.x * 256;
  int m = mask[base + threadIdx.x];
  unsigned long long w = __ballot(m != 0);
  if ((threadIdx.x & 63) == 0) bits[base / 64 + (threadIdx.x >> 6)] = w;
}

// ---------------------------------------------------------------------------
// Kernel 1: QKV projection via MFMA. Q,K stored (b,n,s,e) bf16; V stored
// TRANSPOSED (b,n,e,t) bf16 so PV's B-operand frags are k-contiguous.
// ---------------------------------------------------------------------------
__global__ __launch_bounds__(256) void qkv_mfma(
    const float* __restrict__ H,
    const float* __restrict__ Wq, const float* __restrict__ bq,
    const float* __restrict__ Wk, const float* __restrict__ bk,
    const float* __restrict__ Wv, const float* __restrict__ bv,
    __bf16* __restrict__ Q, __bf16* __restrict__ K, __bf16* __restrict__ Vt) {
  int idx = blockIdx.x;
  int rt = idx & 15, n = (idx >> 4) & 15, b = idx >> 8;
  int tid = threadIdx.x, wave = tid >> 6, lane = tid & 63;
  int quad = lane >> 4, col = lane & 15;
  int s0 = rt * 64 + wave * 16;

  const float* Hrow = H + ((size_t)(b * S_ + s0 + col)) * D_ + n * DH_;
  v8bf af[2];
#pragma unroll
  for (int ks = 0; ks < 2; ks++) {
    const float* p = Hrow + ks * 32 + quad * 8;
    af[ks] = cvt8(*(const float4*)p, *(const float4*)(p + 4));
  }

  const float* Wm[3] = {Wq + n * 4096, Wk + n * 4096, Wv + n * 4096};
  const float* Bm[3] = {bq + n * 64, bk + n * 64, bv + n * 64};
  __bf16* Qdst = Q + ((size_t)(b * NH_ + n) * S_) * DH_;
  __bf16* Kdst = K + ((size_t)(b * NH_ + n) * S_) * DH_;
  __bf16* Vdst = Vt + ((size_t)(b * NH_ + n) * DH_) * S_;

  for (int w = 0; w < 3; w++) {
#pragma unroll
    for (int ct = 0; ct < 4; ct++) {
      int e = ct * 16 + col;
      v4f acc = {0.f, 0.f, 0.f, 0.f};
#pragma unroll
      for (int ks = 0; ks < 2; ks++) {
        const float* p = Wm[w] + (size_t)e * 64 + ks * 32 + quad * 8;
        acc = MFMA(af[ks], cvt8(*(const float4*)p, *(const float4*)(p + 4)), acc);
      }
      float bias = Bm[w][e];
      if (w == 0) {
#pragma unroll
        for (int g = 0; g < 4; g++)
          Qdst[(size_t)(s0 + quad * 4 + g) * DH_ + e] = tobf(acc[g] + bias);
      } else if (w == 1) {
#pragma unroll
        for (int g = 0; g < 4; g++)
          Kdst[(size_t)(s0 + quad * 4 + g) * DH_ + e] = tobf(acc[g] + bias);
      } else {
#pragma unroll
        for (int g = 0; g < 4; g++)
          Vdst[(size_t)e * S_ + s0 + quad * 4 + g] = tobf(acc[g] + bias);
      }
    }
  }
}

// ---------------------------------------------------------------------------
// Kernel 2 (FUSED): QK^T + mask + softmax + A-write + PV, no LDS, no barriers.
//
// Swapped-operand trick: S^T = mfma(K_frag, Q_frag). C-layout puts a lane's 4
// values in ONE Q-row (s0+col) at t = ct*16 + quad*4 + g. So:
//   - softmax stats are per-lane scalars (no in-loop shuffles; 2 shfl_xor at end)
//   - A-write is one float4 per lane per tile (t-consecutive)
//   - the register layout IS the A-fragment of mfma_16x16x16_bf16, so PV fuses
//     in-register (k=16 per ct-tile), killing the 537MB A re-read of the old
//     pv_mfma kernel.
// ---------------------------------------------------------------------------
__global__ __launch_bounds__(256) void attn_pv(
    const __bf16* __restrict__ Q, const __bf16* __restrict__ K,
    const __bf16* __restrict__ Vt, const unsigned long long* __restrict__ mbits,
    float* __restrict__ A, __bf16* __restrict__ X) {
  int idx = blockIdx.x;
  int n = idx & 15, st = (idx >> 4) & 15, b = idx >> 8;
  int tid = threadIdx.x, wave = tid >> 6, lane = tid & 63;
  int quad = lane >> 4, col = lane & 15;
  int s0 = st * 64 + wave * 16;

  // Q as B-operand: lane holds row s0+col, d-contiguous (identical loads to before)
  const __bf16* Qb = Q + ((size_t)(b * NH_ + n) * S_ + s0 + col) * DH_;
  v8bf qf0 = *(const v8bf*)(Qb + quad * 8);
  v8bf qf1 = *(const v8bf*)(Qb + 32 + quad * 8);

  const __bf16* Kb = K + ((size_t)(b * NH_ + n) * S_) * DH_;
  const __bf16* Vb = Vt + ((size_t)(b * NH_ + n) * DH_) * S_;
  // one mask row per lane: row s0+col
  const unsigned long long* mrow = mbits + ((size_t)b * S_ + s0 + col) * (S_ / 64);

  int shb = quad * 4;
  float mx = -INFINITY, l = 0.f;

  // ---- pass 1: per-lane online max+sum over this lane's t-subset ----
  for (int cw = 0; cw < 16; cw++) {
    unsigned long long w = mrow[cw];
#pragma unroll
    for (int c4 = 0; c4 < 4; c4++) {
      int ct = cw * 4 + c4;
      const __bf16* Kt = Kb + (size_t)(ct * 16 + col) * DH_;
      v4f acc = {0.f, 0.f, 0.f, 0.f};
      acc = MFMA(*(const v8bf*)(Kt + quad * 8), qf0, acc);
      acc = MFMA(*(const v8bf*)(Kt + 32 + quad * 8), qf1, acc);
      int sh = c4 * 16 + shb;
      float v0 = ((w >> (sh + 0)) & 1ull) ? acc[0] * 0.125f : NEGV;
      float v1 = ((w >> (sh + 1)) & 1ull) ? acc[1] * 0.125f : NEGV;
      float v2 = ((w >> (sh + 2)) & 1ull) ? acc[2] * 0.125f : NEGV;
      float v3 = ((w >> (sh + 3)) & 1ull) ? acc[3] * 0.125f : NEGV;
      float vm = fmaxf(fmaxf(v0, v1), fmaxf(v2, v3));
      float mnew = fmaxf(mx, vm);
      float e = __expf(v0 - mnew) + __expf(v1 - mnew) +
                __expf(v2 - mnew) + __expf(v3 - mnew);
      l = l * __expf(mx - mnew) + e;
      mx = mnew;
    }
  }

  // ---- merge the 4 quads sharing row s0+col (lanes q*16+col) ----
#pragma unroll
  for (int off = 16; off < 64; off <<= 1) {
    float mo = __shfl_xor(mx, off);
    float lo = __shfl_xor(l, off);
    float M = fmaxf(mx, mo);
    l = l * __expf(mx - M) + lo * __expf(mo - M);
    mx = M;
  }
  float inv = 1.f / l;

  // ---- pass 2: recompute, write normalized A (float4), accumulate PV ----
  float* Ab = A + (((size_t)n * B_ + b) * S_ + s0 + col) * S_;
  v4f opv[4];
#pragma unroll
  for (int d = 0; d < 4; d++) opv[d] = {0.f, 0.f, 0.f, 0.f};

  for (int cw = 0; cw < 16; cw++) {
    unsigned long long w = mrow[cw];
#pragma unroll
    for (int c4 = 0; c4 < 4; c4++) {
      int ct = cw * 4 + c4;
      const __bf16* Kt = Kb + (size_t)(ct * 16 + col) * DH_;
      v4f acc = {0.f, 0.f, 0.f, 0.f};
      acc = MFMA(*(const v8bf*)(Kt + quad * 8), qf0, acc);
      acc = MFMA(*(const v8bf*)(Kt + 32 + quad * 8), qf1, acc);
      int sh = c4 * 16 + shb;
      v4f av;
      v4bf pb;
#pragma unroll
      for (int g = 0; g < 4; g++) {
        float e = __expf(acc[g] * 0.125f - mx) * inv;
        float a = ((w >> (sh + g)) & 1ull) ? e : 0.f;
        av[g] = a;
        pb[g] = tobf(a);
      }
      *(v4f*)(Ab + ct * 16 + quad * 4) = av;  // 16B coalesced A-write
      // PV: P-frag (in regs) x Vt-frag, k=16
#pragma unroll
      for (int d = 0; d < 4; d++) {
        const __bf16* vp = Vb + (size_t)(d * 16 + col) * S_ + ct * 16 + quad * 4;
        opv[d] = mfma_k16(pb, *(const v4bf*)vp, opv[d]);
      }
    }
  }

  // ---- write heads (bf16), same layout as old pv_mfma epilogue ----
#pragma unroll
  for (int d = 0; d < 4; d++)
#pragma unroll
    for (int g = 0; g < 4; g++)
      X[((size_t)(b * S_ + s0 + quad * 4 + g)) * D_ + n * 64 + d * 16 + col] =
          tobf(opv[d][g]);
}

// ---------------------------------------------------------------------------
// Kernel 3: out = X @ Wo^T + bo via MFMA. X bf16 (heads), Wo fp32.
// ---------------------------------------------------------------------------
__global__ __launch_bounds__(256) void oproj_mfma(
    const __bf16* __restrict__ X, const float* __restrict__ Wo,
    const float* __restrict__ bo, float* __restrict__ out) {
  int idx = blockIdx.x;
  int nt = idx & 15, mt = idx >> 4;
  int tid = threadIdx.x, wave = tid >> 6, lane = tid & 63;
  int quad = lane >> 4, col = lane & 15;
  int m0 = mt * 64 + wave * 16, o0 = nt * 64;

  const __bf16* Xb = X + (size_t)(m0 + col) * D_;

  v4f acc[4];
#pragma unroll
  for (int ct = 0; ct < 4; ct++) acc[ct] = {0.f, 0.f, 0.f, 0.f};

  for (int k0 = 0; k0 < D_; k0 += 32) {
    v8bf a8 = *(const v8bf*)(Xb + k0 + quad * 8);
#pragma unroll
    for (int ct = 0; ct < 4; ct++) {
      const float* p = Wo + (size_t)(o0 + ct * 16 + col) * D_ + k0 + quad * 8;
      acc[ct] = MFMA(a8, cvt8(*(const float4*)p, *(const float4*)(p + 4)), acc[ct]);
    }
  }
#pragma unroll
  for (int ct = 0; ct < 4; ct++) {
    int o = o0 + ct * 16 + col;
    float bias = bo[o];
#pragma unroll
    for (int g = 0; g < 4; g++)
      out[(size_t)(m0 + quad * 4 + g) * D_ + o] = acc[ct][g] + bias;
  }
}

// ---------------------------------------------------------------------------
extern "C" void kernel_launch(void* const* d_in, const int* in_sizes, int n_in,
                              void* d_out, int out_size, void* d_ws,
                              size_t ws_size, hipStream_t stream) {
  const float* H = (const float*)d_in[0];
  const int* mask = (const int*)d_in[1];
  const float* Wq = (const float*)d_in[2];
  const float* bq = (const float*)d_in[3];
  const float* Wk = (const float*)d_in[4];
  const float* bk = (const float*)d_in[5];
  const float* Wv = (const float*)d_in[6];
  const float* bv = (const float*)d_in[7];
  const float* Wo = (const float*)d_in[8];
  const float* bo = (const float*)d_in[9];

  float* out = (float*)d_out;                      // (B,S,D)
  float* A = out + (size_t)B_ * S_ * D_;           // (NH,B,S,S)

  const size_t qkv_elems = (size_t)B_ * NH_ * S_ * DH_;  // 8.4M
  unsigned long long* mbits = (unsigned long long*)d_ws;          // 1 MB
  __bf16* Q = (__bf16*)(mbits + (size_t)B_ * S_ * (S_ / 64));
  __bf16* K = Q + qkv_elems;
  __bf16* Vt = K + qkv_elems;
  __bf16* X = Vt + qkv_elems;                      // heads, (B,S,D) bf16

  maskpack<<<B_ * S_ * (S_ / 256), 256, 0, stream>>>(mask, mbits);
  qkv_mfma<<<B_ * NH_ * (S_ / 64), 256, 0, stream>>>(H, Wq, bq, Wk, bk, Wv, bv,
                                                     Q, K, Vt);
  attn_pv<<<B_ * (S_ / 64) * NH_, 256, 0, stream>>>(Q, K, Vt, mbits, A, X);
  oproj_mfma<<<(B_ * S_ / 64) * (D_ / 64), 256, 0, stream>>>(X, Wo, bo, out);
}

// Round 2
// 990.609 us; speedup vs baseline: 1.5135x; 1.4140x over previous
//
#include <hip/hip_runtime.h>
#include <hip/hip_bf16.h>

typedef __bf16 v8bf __attribute__((ext_vector_type(8)));
typedef __bf16 v4bf __attribute__((ext_vector_type(4)));
typedef short v4ss __attribute__((ext_vector_type(4)));
typedef float v4f __attribute__((ext_vector_type(4)));

constexpr int B_ = 8, S_ = 1024, D_ = 1024, NH_ = 16, DH_ = 64;
constexpr float NEGV = -1e9f;

#define MFMA(a, b, c) __builtin_amdgcn_mfma_f32_16x16x32_bf16((a), (b), (c), 0, 0, 0)

// k=16 bf16 MFMA: builtin name varies across ROCm; instruction exists on gfx950.
__device__ __forceinline__ v4f mfma_k16(v4bf a, v4bf b, v4f c) {
#if __has_builtin(__builtin_amdgcn_mfma_f32_16x16x16bf16_1k)
  return __builtin_amdgcn_mfma_f32_16x16x16bf16_1k(
      __builtin_bit_cast(v4ss, a), __builtin_bit_cast(v4ss, b), c, 0, 0, 0);
#elif __has_builtin(__builtin_amdgcn_mfma_f32_16x16x16_bf16)
  return __builtin_amdgcn_mfma_f32_16x16x16_bf16(a, b, c, 0, 0, 0);
#else
  v4f d;
  asm volatile("v_mfma_f32_16x16x16_bf16 %0, %1, %2, %3\n\ts_nop 7\n\ts_nop 7"
               : "=v"(d)
               : "v"(a), "v"(b), "v"(c));
  return d;
#endif
}

__device__ __forceinline__ __bf16 tobf(float f) {
  unsigned u = __float_as_uint(f);
  u += 0x7fffu + ((u >> 16) & 1);
  unsigned short s = (unsigned short)(u >> 16);
  return __builtin_bit_cast(__bf16, s);
}

__device__ __forceinline__ v8bf cvt8(float4 a, float4 b) {
  v8bf r;
  r[0] = tobf(a.x); r[1] = tobf(a.y); r[2] = tobf(a.z); r[3] = tobf(a.w);
  r[4] = tobf(b.x); r[5] = tobf(b.y); r[6] = tobf(b.z); r[7] = tobf(b.w);
  return r;
}

// async global->LDS, 16B per lane; LDS dest = wave-uniform base + lane*16
typedef __attribute__((address_space(3))) unsigned lds_uint;
typedef __attribute__((address_space(1))) unsigned gbl_uint;
__device__ __forceinline__ void gload_lds16(const void* g, void* l) {
  __builtin_amdgcn_global_load_lds((const gbl_uint*)g, (lds_uint*)l, 16, 0, 0);
}

// Stage one 64-row x 128B K-chunk into LDS, XOR-swizzled on the GLOBAL side
// (rule: linear LDS dest + inverse-swizzled source + swizzled read).
__device__ __forceinline__ void stage_k(const __bf16* Kb, int chunk, char* buf,
                                        int wave, int lane) {
  const char* src = (const char*)(Kb + (size_t)chunk * 64 * DH_);
#pragma unroll
  for (int h = 0; h < 2; ++h) {
    int i = wave * 128 + h * 64 + lane;      // 16B-unit linear dest index
    int row = i >> 3, cd = i & 7;
    const char* g = src + row * 128 + ((cd ^ (row & 7)) << 4);
    char* l = buf + (wave * 2048 + h * 1024);  // wave-uniform base
    gload_lds16(g, l);
  }
}

// swizzled K-frag read: global 16B-chunk gc of row -> lds chunk gc^(row&7)
__device__ __forceinline__ v8bf lds_k(const char* buf, int row, int gc) {
  return *(const v8bf*)(buf + row * 128 + ((gc ^ (row & 7)) << 4));
}

__device__ __forceinline__ void vload(v4bf* dst, const __bf16* Vb, int ct,
                                      int quad, int col) {
#pragma unroll
  for (int d = 0; d < 4; ++d)
    dst[d] = *(const v4bf*)(Vb + (size_t)(d * 16 + col) * S_ + ct * 16 + quad * 4);
}

// ---------------------------------------------------------------------------
// Kernel 0a: pack mask (B,S,S) int32 -> bitmask u64. 33.5MB -> 1MB
// ---------------------------------------------------------------------------
__global__ __launch_bounds__(256) void maskpack(const int* __restrict__ mask,
                                                unsigned long long* __restrict__ bits) {
  size_t base = (size_t)blockIdx.x * 256;
  int m = mask[base + threadIdx.x];
  unsigned long long w = __ballot(m != 0);
  if ((threadIdx.x & 63) == 0) bits[base / 64 + (threadIdx.x >> 6)] = w;
}

// ---------------------------------------------------------------------------
// Kernel 0b: pack all weights fp32 -> bf16 once, so hot GEMM loops load v8bf
// directly instead of cvt8 (24 VALU) per MFMA. dst: [Wq 64K][Wk 64K][Wv 64K][Wo 1M]
// ---------------------------------------------------------------------------
__global__ __launch_bounds__(256) void wpack(const float* __restrict__ Wq,
                                             const float* __restrict__ Wk,
                                             const float* __restrict__ Wv,
                                             const float* __restrict__ Wo,
                                             __bf16* __restrict__ dst) {
  int i = blockIdx.x * 256 + threadIdx.x;
  float v;
  if (i < 65536) v = Wq[i];
  else if (i < 131072) v = Wk[i - 65536];
  else if (i < 196608) v = Wv[i - 131072];
  else v = Wo[i - 196608];
  dst[i] = tobf(v);
}

// ---------------------------------------------------------------------------
// Kernel 1: QKV projection via MFMA (bf16 weights). Q is PRE-SCALED by 1/8
// so attn never multiplies scores. V stored transposed (b,n,e,t).
// ---------------------------------------------------------------------------
__global__ __launch_bounds__(256) void qkv_mfma(
    const float* __restrict__ H, const __bf16* __restrict__ Wb,
    const float* __restrict__ bq, const float* __restrict__ bk,
    const float* __restrict__ bv,
    __bf16* __restrict__ Q, __bf16* __restrict__ K, __bf16* __restrict__ Vt) {
  int idx = blockIdx.x;
  int rt = idx & 15, n = (idx >> 4) & 15, b = idx >> 8;
  int tid = threadIdx.x, wave = tid >> 6, lane = tid & 63;
  int quad = lane >> 4, col = lane & 15;
  int s0 = rt * 64 + wave * 16;

  const float* Hrow = H + ((size_t)(b * S_ + s0 + col)) * D_ + n * DH_;
  v8bf af[2];
#pragma unroll
  for (int ks = 0; ks < 2; ks++) {
    const float* p = Hrow + ks * 32 + quad * 8;
    af[ks] = cvt8(*(const float4*)p, *(const float4*)(p + 4));
  }

  const __bf16* Wm[3] = {Wb + n * 4096, Wb + 65536 + n * 4096,
                         Wb + 131072 + n * 4096};
  const float* Bm[3] = {bq + n * 64, bk + n * 64, bv + n * 64};
  __bf16* Qdst = Q + ((size_t)(b * NH_ + n) * S_) * DH_;
  __bf16* Kdst = K + ((size_t)(b * NH_ + n) * S_) * DH_;
  __bf16* Vdst = Vt + ((size_t)(b * NH_ + n) * DH_) * S_;

#pragma unroll
  for (int w = 0; w < 3; w++) {
#pragma unroll
    for (int ct = 0; ct < 4; ct++) {
      int e = ct * 16 + col;
      v4f acc = {0.f, 0.f, 0.f, 0.f};
#pragma unroll
      for (int ks = 0; ks < 2; ks++) {
        const __bf16* p = Wm[w] + (size_t)e * 64 + ks * 32 + quad * 8;
        acc = MFMA(af[ks], *(const v8bf*)p, acc);
      }
      float bias = Bm[w][e];
      if (w == 0) {
#pragma unroll
        for (int g = 0; g < 4; g++)
          Qdst[(size_t)(s0 + quad * 4 + g) * DH_ + e] =
              tobf((acc[g] + bias) * 0.125f);
      } else if (w == 1) {
#pragma unroll
        for (int g = 0; g < 4; g++)
          Kdst[(size_t)(s0 + quad * 4 + g) * DH_ + e] = tobf(acc[g] + bias);
      } else {
#pragma unroll
        for (int g = 0; g < 4; g++)
          Vdst[(size_t)e * S_ + s0 + quad * 4 + g] = tobf(acc[g] + bias);
      }
    }
  }
}

// ---------------------------------------------------------------------------
// Kernel 2 (FUSED, LDS-pipelined): QK^T + mask + softmax + A-write + PV.
// K double-buffered in LDS via async global_load_lds (shared by all 4 waves,
// 4x fewer L2 requests), XOR-swizzled for bank-balanced ds_read_b128.
// V + mask register-prefetched one tile/chunk ahead. A written non-temporal
// so the 537MB stream doesn't evict K/V from L2.
// ---------------------------------------------------------------------------
__global__ __launch_bounds__(256, 4) void attn_pv(
    const __bf16* __restrict__ Q, const __bf16* __restrict__ K,
    const __bf16* __restrict__ Vt, const unsigned long long* __restrict__ mbits,
    float* __restrict__ A, __bf16* __restrict__ X) {
  __shared__ __align__(16) char kbuf[2][64 * 128];  // 2 x 8KB K chunks

  int idx = blockIdx.x;
  int n = idx & 15, st = (idx >> 4) & 15, b = idx >> 8;
  int tid = threadIdx.x, wave = tid >> 6, lane = tid & 63;
  int quad = lane >> 4, col = lane & 15;
  int s0 = st * 64 + wave * 16;

  const __bf16* Qb = Q + ((size_t)(b * NH_ + n) * S_ + s0 + col) * DH_;
  v8bf qf0 = *(const v8bf*)(Qb + quad * 8);
  v8bf qf1 = *(const v8bf*)(Qb + 32 + quad * 8);

  const __bf16* Kb = K + ((size_t)(b * NH_ + n) * S_) * DH_;
  const __bf16* Vb = Vt + ((size_t)(b * NH_ + n) * DH_) * S_;
  const unsigned long long* mrow = mbits + ((size_t)b * S_ + s0 + col) * (S_ / 64);

  int shb = quad * 4;
  float mx = -INFINITY, l = 0.f;

  // ================= pass 1: online row max + sum =================
  stage_k(Kb, 0, kbuf[0], wave, lane);
  unsigned long long mw = mrow[0], mwn = 0;

  for (int c = 0; c < 16; ++c) {
    __syncthreads();  // kbuf[c&1] ready; all waves done with kbuf[(c+1)&1]
    if (c + 1 < 16) {
      stage_k(Kb, c + 1, kbuf[(c + 1) & 1], wave, lane);  // overlaps compute
      mwn = mrow[c + 1];
    } else {
      mwn = mw;
    }
    const char* buf = kbuf[c & 1];
#pragma unroll
    for (int tl = 0; tl < 4; ++tl) {
      int row = tl * 16 + col;
      v4f acc = {0.f, 0.f, 0.f, 0.f};
      acc = MFMA(lds_k(buf, row, quad), qf0, acc);
      acc = MFMA(lds_k(buf, row, quad + 4), qf1, acc);
      int sh = tl * 16 + shb;
      float v0 = ((mw >> (sh + 0)) & 1ull) ? acc[0] : NEGV;
      float v1 = ((mw >> (sh + 1)) & 1ull) ? acc[1] : NEGV;
      float v2 = ((mw >> (sh + 2)) & 1ull) ? acc[2] : NEGV;
      float v3 = ((mw >> (sh + 3)) & 1ull) ? acc[3] : NEGV;
      float vm = fmaxf(fmaxf(v0, v1), fmaxf(v2, v3));
      float mnew = fmaxf(mx, vm);
      float e = __expf(v0 - mnew) + __expf(v1 - mnew) +
                __expf(v2 - mnew) + __expf(v3 - mnew);
      l = l * __expf(mx - mnew) + e;
      mx = mnew;
    }
    mw = mwn;
  }

  // merge the 4 quads sharing row s0+col
#pragma unroll
  for (int off = 16; off < 64; off <<= 1) {
    float mo = __shfl_xor(mx, off);
    float lo = __shfl_xor(l, off);
    float M = fmaxf(mx, mo);
    l = l * __expf(mx - M) + lo * __expf(mo - M);
    mx = M;
  }
  float inv = 1.f / l;

  // ================= pass 2: normalize, write A, accumulate PV =================
  float* Ab = A + (((size_t)n * B_ + b) * S_ + s0 + col) * S_;
  v4f opv[4];
#pragma unroll
  for (int d = 0; d < 4; ++d) opv[d] = {0.f, 0.f, 0.f, 0.f};

  stage_k(Kb, 0, kbuf[0], wave, lane);  // safe: pass1 c=15 reads kbuf[1]
  v4bf vb0[4], vb1[4];
  vload(vb0, Vb, 0, quad, col);
  unsigned long long mw2 = mrow[0], mwn2 = 0;

  for (int c = 0; c < 16; ++c) {
    __syncthreads();
    if (c + 1 < 16) {
      stage_k(Kb, c + 1, kbuf[(c + 1) & 1], wave, lane);
      mwn2 = mrow[c + 1];
    } else {
      mwn2 = mw2;
    }
    const char* buf = kbuf[c & 1];
#pragma unroll
    for (int tl = 0; tl < 4; ++tl) {
      int ct = c * 4 + tl;
      v4bf* vcur = (tl & 1) ? vb1 : vb0;
      v4bf* vnext = (tl & 1) ? vb0 : vb1;
      if (ct + 1 < 64) vload(vnext, Vb, ct + 1, quad, col);  // prefetch
      int row = tl * 16 + col;
      v4f acc = {0.f, 0.f, 0.f, 0.f};
      acc = MFMA(lds_k(buf, row, quad), qf0, acc);
      acc = MFMA(lds_k(buf, row, quad + 4), qf1, acc);
      int sh = tl * 16 + shb;
      v4f av;
      v4bf pb;
#pragma unroll
      for (int g = 0; g < 4; ++g) {
        float e = __expf(acc[g] - mx) * inv;
        float a = ((mw2 >> (sh + g)) & 1ull) ? e : 0.f;
        av[g] = a;
        pb[g] = tobf(a);
      }
      __builtin_nontemporal_store(av, (v4f*)(Ab + ct * 16 + quad * 4));
#pragma unroll
      for (int d = 0; d < 4; ++d) opv[d] = mfma_k16(pb, vcur[d], opv[d]);
    }
    mw2 = mwn2;
  }

  // write heads (bf16); X is re-read by oproj -> normal stores
#pragma unroll
  for (int d = 0; d < 4; ++d)
#pragma unroll
    for (int g = 0; g < 4; ++g)
      X[((size_t)(b * S_ + s0 + quad * 4 + g)) * D_ + n * 64 + d * 16 + col] =
          tobf(opv[d][g]);
}

// ---------------------------------------------------------------------------
// Kernel 3: out = X @ Wo^T + bo via MFMA. X bf16, Wo pre-packed bf16.
// ---------------------------------------------------------------------------
__global__ __launch_bounds__(256) void oproj_mfma(
    const __bf16* __restrict__ X, const __bf16* __restrict__ Wob,
    const float* __restrict__ bo, float* __restrict__ out) {
  int idx = blockIdx.x;
  int nt = idx & 15, mt = idx >> 4;
  int tid = threadIdx.x, wave = tid >> 6, lane = tid & 63;
  int quad = lane >> 4, col = lane & 15;
  int m0 = mt * 64 + wave * 16, o0 = nt * 64;

  const __bf16* Xb = X + (size_t)(m0 + col) * D_;

  v4f acc[4];
#pragma unroll
  for (int ct = 0; ct < 4; ct++) acc[ct] = {0.f, 0.f, 0.f, 0.f};

  for (int k0 = 0; k0 < D_; k0 += 32) {
    v8bf a8 = *(const v8bf*)(Xb + k0 + quad * 8);
#pragma unroll
    for (int ct = 0; ct < 4; ct++) {
      const __bf16* p = Wob + (size_t)(o0 + ct * 16 + col) * D_ + k0 + quad * 8;
      acc[ct] = MFMA(a8, *(const v8bf*)p, acc[ct]);
    }
  }
#pragma unroll
  for (int ct = 0; ct < 4; ct++) {
    int o = o0 + ct * 16 + col;
    float bias = bo[o];
#pragma unroll
    for (int g = 0; g < 4; g++)
      __builtin_nontemporal_store(
          acc[ct][g] + bias, &out[(size_t)(m0 + quad * 4 + g) * D_ + o]);
  }
}

// ---------------------------------------------------------------------------
extern "C" void kernel_launch(void* const* d_in, const int* in_sizes, int n_in,
                              void* d_out, int out_size, void* d_ws,
                              size_t ws_size, hipStream_t stream) {
  const float* H = (const float*)d_in[0];
  const int* mask = (const int*)d_in[1];
  const float* Wq = (const float*)d_in[2];
  const float* bq = (const float*)d_in[3];
  const float* Wk = (const float*)d_in[4];
  const float* bk = (const float*)d_in[5];
  const float* Wv = (const float*)d_in[6];
  const float* bv = (const float*)d_in[7];
  const float* Wo = (const float*)d_in[8];
  const float* bo = (const float*)d_in[9];

  float* out = (float*)d_out;                      // (B,S,D)
  float* A = out + (size_t)B_ * S_ * D_;           // (NH,B,S,S)

  const size_t qkv_elems = (size_t)B_ * NH_ * S_ * DH_;  // 8.4M
  unsigned long long* mbits = (unsigned long long*)d_ws;          // 1 MB
  __bf16* Q = (__bf16*)(mbits + (size_t)B_ * S_ * (S_ / 64));
  __bf16* K = Q + qkv_elems;
  __bf16* Vt = K + qkv_elems;
  __bf16* X = Vt + qkv_elems;                      // heads, (B,S,D) bf16
  __bf16* Wb = X + qkv_elems;                      // packed weights, 2.44 MB
  __bf16* Wob = Wb + 196608;

  wpack<<<4864, 256, 0, stream>>>(Wq, Wk, Wv, Wo, Wb);
  maskpack<<<B_ * S_ * (S_ / 256), 256, 0, stream>>>(mask, mbits);
  qkv_mfma<<<B_ * NH_ * (S_ / 64), 256, 0, stream>>>(H, Wb, bq, bk, bv, Q, K, Vt);
  attn_pv<<<B_ * (S_ / 64) * NH_, 256, 0, stream>>>(Q, K, Vt, mbits, A, X);
  oproj_mfma<<<(B_ * S_ / 64) * (D_ / 64), 256, 0, stream>>>(X, Wob, bo, out);
}

// Round 3
// 873.240 us; speedup vs baseline: 1.7169x; 1.1344x over previous
//
#include <hip/hip_runtime.h>
#include <hip/hip_bf16.h>

typedef __bf16 v8bf __attribute__((ext_vector_type(8)));
typedef __bf16 v4bf __attribute__((ext_vector_type(4)));
typedef short v4ss __attribute__((ext_vector_type(4)));
typedef float v4f __attribute__((ext_vector_type(4)));

constexpr int B_ = 8, S_ = 1024, D_ = 1024, NH_ = 16, DH_ = 64;
constexpr float NEGV = -1e9f;

#define MFMA(a, b, c) __builtin_amdgcn_mfma_f32_16x16x32_bf16((a), (b), (c), 0, 0, 0)

// k=16 bf16 MFMA: builtin name varies across ROCm; instruction exists on gfx950.
__device__ __forceinline__ v4f mfma_k16(v4bf a, v4bf b, v4f c) {
#if __has_builtin(__builtin_amdgcn_mfma_f32_16x16x16bf16_1k)
  return __builtin_amdgcn_mfma_f32_16x16x16bf16_1k(
      __builtin_bit_cast(v4ss, a), __builtin_bit_cast(v4ss, b), c, 0, 0, 0);
#elif __has_builtin(__builtin_amdgcn_mfma_f32_16x16x16_bf16)
  return __builtin_amdgcn_mfma_f32_16x16x16_bf16(a, b, c, 0, 0, 0);
#else
  v4f d;
  asm volatile("v_mfma_f32_16x16x16_bf16 %0, %1, %2, %3\n\ts_nop 7\n\ts_nop 7"
               : "=v"(d)
               : "v"(a), "v"(b), "v"(c));
  return d;
#endif
}

__device__ __forceinline__ __bf16 tobf(float f) {
  unsigned u = __float_as_uint(f);
  u += 0x7fffu + ((u >> 16) & 1);
  unsigned short s = (unsigned short)(u >> 16);
  return __builtin_bit_cast(__bf16, s);
}

__device__ __forceinline__ v8bf cvt8(float4 a, float4 b) {
  v8bf r;
  r[0] = tobf(a.x); r[1] = tobf(a.y); r[2] = tobf(a.z); r[3] = tobf(a.w);
  r[4] = tobf(b.x); r[5] = tobf(b.y); r[6] = tobf(b.z); r[7] = tobf(b.w);
  return r;
}

// async global->LDS, 16B per lane; LDS dest = wave-uniform base + lane*16
typedef __attribute__((address_space(3))) unsigned lds_uint;
typedef __attribute__((address_space(1))) unsigned gbl_uint;
__device__ __forceinline__ void gload_lds16(const void* g, void* l) {
  __builtin_amdgcn_global_load_lds((const gbl_uint*)g, (lds_uint*)l, 16, 0, 0);
}

// Stage a 64-row x 128B tile (rows strided `stride` bytes in global) into an
// 8KB LDS buffer, XOR-swizzled on the GLOBAL side (rule #21: linear LDS dest +
// inverse-swizzled source + swizzled read). 2 DMAs per thread, 256 threads.
__device__ __forceinline__ void stage_tile(const char* src, size_t stride,
                                           char* buf, int wave, int lane) {
#pragma unroll
  for (int h = 0; h < 2; ++h) {
    int i = wave * 128 + h * 64 + lane;      // 16B-unit linear dest index
    int row = i >> 3, cd = i & 7;
    const char* g = src + (size_t)row * stride + ((cd ^ (row & 7)) << 4);
    char* l = buf + (wave * 2048 + h * 1024);  // wave-uniform base
    gload_lds16(g, l);
  }
}

// swizzled frag read: global 16B-chunk gc of row -> lds chunk gc^(row&7)
__device__ __forceinline__ v8bf lds_k(const char* buf, int row, int gc) {
  return *(const v8bf*)(buf + row * 128 + ((gc ^ (row & 7)) << 4));
}

__device__ __forceinline__ void vload(v4bf* dst, const __bf16* Vb, int ct,
                                      int quad, int col) {
#pragma unroll
  for (int d = 0; d < 4; ++d)
    dst[d] = *(const v4bf*)(Vb + (size_t)(d * 16 + col) * S_ + ct * 16 + quad * 4);
}

// ---------------------------------------------------------------------------
// Kernel 0a: pack mask (B,S,S) int32 -> bitmask u64. 33.5MB -> 1MB
// ---------------------------------------------------------------------------
__global__ __launch_bounds__(256) void maskpack(const int* __restrict__ mask,
                                                unsigned long long* __restrict__ bits) {
  size_t base = (size_t)blockIdx.x * 256;
  int m = mask[base + threadIdx.x];
  unsigned long long w = __ballot(m != 0);
  if ((threadIdx.x & 63) == 0) bits[base / 64 + (threadIdx.x >> 6)] = w;
}

// ---------------------------------------------------------------------------
// Kernel 0b: pack all weights fp32 -> bf16 once.
// dst: [Wq 64K][Wk 64K][Wv 64K][Wo 1M] elements
// ---------------------------------------------------------------------------
__global__ __launch_bounds__(256) void wpack(const float* __restrict__ Wq,
                                             const float* __restrict__ Wk,
                                             const float* __restrict__ Wv,
                                             const float* __restrict__ Wo,
                                             __bf16* __restrict__ dst) {
  int i = blockIdx.x * 256 + threadIdx.x;
  float v;
  if (i < 65536) v = Wq[i];
  else if (i < 131072) v = Wk[i - 65536];
  else if (i < 196608) v = Wv[i - 131072];
  else v = Wo[i - 196608];
  dst[i] = tobf(v);
}

// ---------------------------------------------------------------------------
// Kernel 1: QKV projection via MFMA. Weight slabs (3 x 8KB bf16) staged in LDS
// once per block (shared by all 4 waves; was 4x-redundant L2 loads in the hot
// loop). Q pre-scaled by 1/8. V stored transposed (b,n,e,t), 8B vector store.
// ---------------------------------------------------------------------------
__global__ __launch_bounds__(256) void qkv_mfma(
    const float* __restrict__ H, const __bf16* __restrict__ Wb,
    const float* __restrict__ bq, const float* __restrict__ bk,
    const float* __restrict__ bv,
    __bf16* __restrict__ Q, __bf16* __restrict__ K, __bf16* __restrict__ Vt) {
  __shared__ __align__(16) char wlds[3][64 * 128];  // q,k,v weight slabs

  int idx = blockIdx.x;
  int rt = idx & 15, n = (idx >> 4) & 15, b = idx >> 8;
  int tid = threadIdx.x, wave = tid >> 6, lane = tid & 63;
  int quad = lane >> 4, col = lane & 15;
  int s0 = rt * 64 + wave * 16;

  // stage weight slabs (row e, 128B contiguous)
  stage_tile((const char*)(Wb + n * 4096), 128, wlds[0], wave, lane);
  stage_tile((const char*)(Wb + 65536 + n * 4096), 128, wlds[1], wave, lane);
  stage_tile((const char*)(Wb + 131072 + n * 4096), 128, wlds[2], wave, lane);

  const float* Hrow = H + ((size_t)(b * S_ + s0 + col)) * D_ + n * DH_;
  v8bf af[2];
#pragma unroll
  for (int ks = 0; ks < 2; ks++) {
    const float* p = Hrow + ks * 32 + quad * 8;
    af[ks] = cvt8(*(const float4*)p, *(const float4*)(p + 4));
  }

  const float* Bm[3] = {bq + n * 64, bk + n * 64, bv + n * 64};
  __bf16* Qdst = Q + ((size_t)(b * NH_ + n) * S_) * DH_;
  __bf16* Kdst = K + ((size_t)(b * NH_ + n) * S_) * DH_;
  __bf16* Vdst = Vt + ((size_t)(b * NH_ + n) * DH_) * S_;

  __syncthreads();  // weight slabs ready

#pragma unroll
  for (int w = 0; w < 3; w++) {
#pragma unroll
    for (int ct = 0; ct < 4; ct++) {
      int e = ct * 16 + col;
      v4f acc = {0.f, 0.f, 0.f, 0.f};
      acc = MFMA(af[0], lds_k(wlds[w], e, quad), acc);
      acc = MFMA(af[1], lds_k(wlds[w], e, quad + 4), acc);
      float bias = Bm[w][e];
      if (w == 0) {
#pragma unroll
        for (int g = 0; g < 4; g++)
          Qdst[(size_t)(s0 + quad * 4 + g) * DH_ + e] =
              tobf((acc[g] + bias) * 0.125f);
      } else if (w == 1) {
#pragma unroll
        for (int g = 0; g < 4; g++)
          Kdst[(size_t)(s0 + quad * 4 + g) * DH_ + e] = tobf(acc[g] + bias);
      } else {
        v4bf pv;
#pragma unroll
        for (int g = 0; g < 4; g++) pv[g] = tobf(acc[g] + bias);
        *(v4bf*)(Vdst + (size_t)e * S_ + s0 + quad * 4) = pv;  // 8B store
      }
    }
  }
}

// ---------------------------------------------------------------------------
// Kernel 2 (FUSED, LDS-pipelined): QK^T + mask + softmax + A-write + PV.
// (unchanged from round 2)
// ---------------------------------------------------------------------------
__global__ __launch_bounds__(256, 4) void attn_pv(
    const __bf16* __restrict__ Q, const __bf16* __restrict__ K,
    const __bf16* __restrict__ Vt, const unsigned long long* __restrict__ mbits,
    float* __restrict__ A, __bf16* __restrict__ X) {
  __shared__ __align__(16) char kbuf[2][64 * 128];  // 2 x 8KB K chunks

  int idx = blockIdx.x;
  int n = idx & 15, st = (idx >> 4) & 15, b = idx >> 8;
  int tid = threadIdx.x, wave = tid >> 6, lane = tid & 63;
  int quad = lane >> 4, col = lane & 15;
  int s0 = st * 64 + wave * 16;

  const __bf16* Qb = Q + ((size_t)(b * NH_ + n) * S_ + s0 + col) * DH_;
  v8bf qf0 = *(const v8bf*)(Qb + quad * 8);
  v8bf qf1 = *(const v8bf*)(Qb + 32 + quad * 8);

  const __bf16* Kb = K + ((size_t)(b * NH_ + n) * S_) * DH_;
  const __bf16* Vb = Vt + ((size_t)(b * NH_ + n) * DH_) * S_;
  const unsigned long long* mrow = mbits + ((size_t)b * S_ + s0 + col) * (S_ / 64);

  int shb = quad * 4;
  float mx = -INFINITY, l = 0.f;

  // ================= pass 1: online row max + sum =================
  stage_tile((const char*)Kb, 128, kbuf[0], wave, lane);
  unsigned long long mw = mrow[0], mwn = 0;

  for (int c = 0; c < 16; ++c) {
    __syncthreads();  // kbuf[c&1] ready; all waves done with kbuf[(c+1)&1]
    if (c + 1 < 16) {
      stage_tile((const char*)(Kb + (size_t)(c + 1) * 64 * DH_), 128,
                 kbuf[(c + 1) & 1], wave, lane);  // overlaps compute
      mwn = mrow[c + 1];
    } else {
      mwn = mw;
    }
    const char* buf = kbuf[c & 1];
#pragma unroll
    for (int tl = 0; tl < 4; ++tl) {
      int row = tl * 16 + col;
      v4f acc = {0.f, 0.f, 0.f, 0.f};
      acc = MFMA(lds_k(buf, row, quad), qf0, acc);
      acc = MFMA(lds_k(buf, row, quad + 4), qf1, acc);
      int sh = tl * 16 + shb;
      float v0 = ((mw >> (sh + 0)) & 1ull) ? acc[0] : NEGV;
      float v1 = ((mw >> (sh + 1)) & 1ull) ? acc[1] : NEGV;
      float v2 = ((mw >> (sh + 2)) & 1ull) ? acc[2] : NEGV;
      float v3 = ((mw >> (sh + 3)) & 1ull) ? acc[3] : NEGV;
      float vm = fmaxf(fmaxf(v0, v1), fmaxf(v2, v3));
      float mnew = fmaxf(mx, vm);
      float e = __expf(v0 - mnew) + __expf(v1 - mnew) +
                __expf(v2 - mnew) + __expf(v3 - mnew);
      l = l * __expf(mx - mnew) + e;
      mx = mnew;
    }
    mw = mwn;
  }

  // merge the 4 quads sharing row s0+col
#pragma unroll
  for (int off = 16; off < 64; off <<= 1) {
    float mo = __shfl_xor(mx, off);
    float lo = __shfl_xor(l, off);
    float M = fmaxf(mx, mo);
    l = l * __expf(mx - M) + lo * __expf(mo - M);
    mx = M;
  }
  float inv = 1.f / l;

  // ================= pass 2: normalize, write A, accumulate PV =================
  float* Ab = A + (((size_t)n * B_ + b) * S_ + s0 + col) * S_;
  v4f opv[4];
#pragma unroll
  for (int d = 0; d < 4; ++d) opv[d] = {0.f, 0.f, 0.f, 0.f};

  stage_tile((const char*)Kb, 128, kbuf[0], wave, lane);  // pass1 c=15 read kbuf[1]
  v4bf vb0[4], vb1[4];
  vload(vb0, Vb, 0, quad, col);
  unsigned long long mw2 = mrow[0], mwn2 = 0;

  for (int c = 0; c < 16; ++c) {
    __syncthreads();
    if (c + 1 < 16) {
      stage_tile((const char*)(Kb + (size_t)(c + 1) * 64 * DH_), 128,
                 kbuf[(c + 1) & 1], wave, lane);
      mwn2 = mrow[c + 1];
    } else {
      mwn2 = mw2;
    }
    const char* buf = kbuf[c & 1];
#pragma unroll
    for (int tl = 0; tl < 4; ++tl) {
      int ct = c * 4 + tl;
      v4bf* vcur = (tl & 1) ? vb1 : vb0;
      v4bf* vnext = (tl & 1) ? vb0 : vb1;
      if (ct + 1 < 64) vload(vnext, Vb, ct + 1, quad, col);  // prefetch
      int row = tl * 16 + col;
      v4f acc = {0.f, 0.f, 0.f, 0.f};
      acc = MFMA(lds_k(buf, row, quad), qf0, acc);
      acc = MFMA(lds_k(buf, row, quad + 4), qf1, acc);
      int sh = tl * 16 + shb;
      v4f av;
      v4bf pb;
#pragma unroll
      for (int g = 0; g < 4; ++g) {
        float e = __expf(acc[g] - mx) * inv;
        float a = ((mw2 >> (sh + g)) & 1ull) ? e : 0.f;
        av[g] = a;
        pb[g] = tobf(a);
      }
      __builtin_nontemporal_store(av, (v4f*)(Ab + ct * 16 + quad * 4));
#pragma unroll
      for (int d = 0; d < 4; ++d) opv[d] = mfma_k16(pb, vcur[d], opv[d]);
    }
    mw2 = mwn2;
  }

  // write heads (bf16); X is re-read by oproj -> normal stores
#pragma unroll
  for (int d = 0; d < 4; ++d)
#pragma unroll
    for (int g = 0; g < 4; ++g)
      X[((size_t)(b * S_ + s0 + quad * 4 + g)) * D_ + n * 64 + d * 16 + col] =
          tobf(opv[d][g]);
}

// ---------------------------------------------------------------------------
// Kernel 3: out = X @ Wo^T + bo. 2-phase staged GEMM: X-tile and Wo-tile
// (8KB each) DMA'd to LDS, double-buffered, one barrier per 64-k step.
// Kills the latency-serialized direct loads (4x-redundant Wo across waves).
// ---------------------------------------------------------------------------
__global__ __launch_bounds__(256) void oproj_mfma(
    const __bf16* __restrict__ X, const __bf16* __restrict__ Wob,
    const float* __restrict__ bo, float* __restrict__ out) {
  __shared__ __align__(16) char xbuf[2][64 * 128];  // 64 m-rows x 64 k
  __shared__ __align__(16) char wbuf[2][64 * 128];  // 64 o-rows x 64 k

  int idx = blockIdx.x;
  int nt = idx & 15, mt = idx >> 4;
  int tid = threadIdx.x, wave = tid >> 6, lane = tid & 63;
  int quad = lane >> 4, col = lane & 15;
  int m0b = mt * 64, o0 = nt * 64;

  const char* Xbase = (const char*)(X + (size_t)m0b * D_);    // row stride 2KB
  const char* Wbase = (const char*)(Wob + (size_t)o0 * D_);   // row stride 2KB

  stage_tile(Xbase, 2048, xbuf[0], wave, lane);
  stage_tile(Wbase, 2048, wbuf[0], wave, lane);

  v4f acc[4];
#pragma unroll
  for (int ct = 0; ct < 4; ct++) acc[ct] = {0.f, 0.f, 0.f, 0.f};

  for (int s = 0; s < 16; ++s) {
    __syncthreads();  // buf[s&1] DMA complete; prior compute done
    if (s + 1 < 16) {
      stage_tile(Xbase + (s + 1) * 128, 2048, xbuf[(s + 1) & 1], wave, lane);
      stage_tile(Wbase + (s + 1) * 128, 2048, wbuf[(s + 1) & 1], wave, lane);
    }
    const char* xb = xbuf[s & 1];
    const char* wb = wbuf[s & 1];
    int mrow = wave * 16 + col;
    v8bf a0 = lds_k(xb, mrow, quad);
    v8bf a1 = lds_k(xb, mrow, quad + 4);
#pragma unroll
    for (int ct = 0; ct < 4; ct++) {
      int orow = ct * 16 + col;
      acc[ct] = MFMA(a0, lds_k(wb, orow, quad), acc[ct]);
      acc[ct] = MFMA(a1, lds_k(wb, orow, quad + 4), acc[ct]);
    }
  }
#pragma unroll
  for (int ct = 0; ct < 4; ct++) {
    int o = o0 + ct * 16 + col;
    float bias = bo[o];
#pragma unroll
    for (int g = 0; g < 4; g++)
      __builtin_nontemporal_store(
          acc[ct][g] + bias,
          &out[(size_t)(m0b + wave * 16 + quad * 4 + g) * D_ + o]);
  }
}

// ---------------------------------------------------------------------------
extern "C" void kernel_launch(void* const* d_in, const int* in_sizes, int n_in,
                              void* d_out, int out_size, void* d_ws,
                              size_t ws_size, hipStream_t stream) {
  const float* H = (const float*)d_in[0];
  const int* mask = (const int*)d_in[1];
  const float* Wq = (const float*)d_in[2];
  const float* bq = (const float*)d_in[3];
  const float* Wk = (const float*)d_in[4];
  const float* bk = (const float*)d_in[5];
  const float* Wv = (const float*)d_in[6];
  const float* bv = (const float*)d_in[7];
  const float* Wo = (const float*)d_in[8];
  const float* bo = (const float*)d_in[9];

  float* out = (float*)d_out;                      // (B,S,D)
  float* A = out + (size_t)B_ * S_ * D_;           // (NH,B,S,S)

  const size_t qkv_elems = (size_t)B_ * NH_ * S_ * DH_;  // 8.4M
  unsigned long long* mbits = (unsigned long long*)d_ws;          // 1 MB
  __bf16* Q = (__bf16*)(mbits + (size_t)B_ * S_ * (S_ / 64));
  __bf16* K = Q + qkv_elems;
  __bf16* Vt = K + qkv_elems;
  __bf16* X = Vt + qkv_elems;                      // heads, (B,S,D) bf16
  __bf16* Wb = X + qkv_elems;                      // packed weights, 2.44 MB
  __bf16* Wob = Wb + 196608;

  wpack<<<4864, 256, 0, stream>>>(Wq, Wk, Wv, Wo, Wb);
  maskpack<<<B_ * S_ * (S_ / 256), 256, 0, stream>>>(mask, mbits);
  qkv_mfma<<<B_ * NH_ * (S_ / 64), 256, 0, stream>>>(H, Wb, bq, bk, bv, Q, K, Vt);
  attn_pv<<<B_ * (S_ / 64) * NH_, 256, 0, stream>>>(Q, K, Vt, mbits, A, X);
  oproj_mfma<<<(B_ * S_ / 64) * (D_ / 64), 256, 0, stream>>>(X, Wob, bo, out);
}